// Round 9
// baseline (131.520 us; speedup 1.0000x reference)
//
#include <hip/hip_runtime.h>
#include <hip/hip_cooperative_groups.h>

namespace cg = cooperative_groups;

#define S 128
#define B 64
#define W 32
#define D2 512
#define DH 512

typedef float floatx4 __attribute__((ext_vector_type(4)));

// d_out layout (floats), concatenated in reference return order
#define OFF_SEN 0
#define OFF_SWH (B * S)                      // 8192
#define OFF_INITH (OFF_SWH + B * S * D2)     // 4202496
#define OFF_CV (OFF_INITH + B * DH)          // 4235264
#define OFF_LOSS (OFF_CV + B * D2)           // 4268032

// ws: u32[0..63] nll bits, u32[64..127] vmask bits. Written fresh every call
// before the grid sync, read only after it -> no initialization needed.

// grid partition (cooperative: must be co-resident; 704 blocks, 16KB LDS, 4 waves)
#define NB_BETA 64
#define NB_INITH 128
#define NB_GATHER 512
#define NB_TOTAL (NB_BETA + NB_INITH + NB_GATHER)

__global__ __launch_bounds__(256) void k_fused(
    const float* __restrict__ h1, const float* __restrict__ h_n1,
    const float* __restrict__ h_n, const float* __restrict__ Wi,
    const float* __restrict__ bi, const int* __restrict__ wiki_sen,
    const int* __restrict__ valid_sen, const int* __restrict__ atten_label,
    float* __restrict__ out, unsigned* __restrict__ ws)
{
    __shared__ float smem[4 * 2 * D2];       // 16 KB (inith); beta uses prefix
    const int bid = blockIdx.x;
    const int tid = threadIdx.x;

    if (bid < NB_BETA) {
        // ---- beta / nll / cv ----
        const int b = bid;
        const int lane = tid & 63;
        const int wv = tid >> 6;             // 4 waves
        const int vs = valid_sen[b];
        const int lbl = atten_label[vs];
        float* sbeta = smem;

        const float* hb = h_n + b * D2;
        const float4 hn0 = ((const float4*)hb)[lane];
        const float4 hn1 = ((const float4*)hb)[64 + lane];

        #pragma unroll
        for (int i = 0; i < 8; ++i) {
            const int w = wv * 8 + i;
            const float* row = h_n1 + (w * B + vs) * D2;
            const float4 a0 = ((const float4*)row)[lane];
            const float4 a1 = ((const float4*)row)[64 + lane];
            float p = a0.x * hn0.x + a0.y * hn0.y + a0.z * hn0.z + a0.w * hn0.w
                    + a1.x * hn1.x + a1.y * hn1.y + a1.z * hn1.z + a1.w * hn1.w;
            #pragma unroll
            for (int m = 32; m >= 1; m >>= 1) p += __shfl_xor(p, m);
            if (lane == 0) sbeta[w] = p;
        }

        // wiki_cv[b,:] = h_n1[lbl, vs, :]
        if (tid < 128) {
            const float4* src = (const float4*)(h_n1 + (lbl * B + vs) * D2);
            float4* dst = (float4*)(out + OFF_CV + b * D2);
            dst[tid] = src[tid];
        }
        __syncthreads();

        if (tid == 0) {
            float mx = sbeta[0];
            for (int w = 1; w < W; ++w) mx = fmaxf(mx, sbeta[w]);
            float Z = 0.0f;
            for (int w = 0; w < W; ++w) Z += expf(sbeta[w] - mx);
            const float nll = -(sbeta[lbl] - mx - logf(Z));
            const float vmask = (lbl != 0) ? 1.0f : 0.0f;
            // coherence-point writes, visible after grid sync
            atomicExch(&ws[b], __float_as_uint(nll));
            atomicExch(&ws[B + b], __float_as_uint(vmask));
        }
    } else if (bid < NB_BETA + NB_INITH) {
        // ---- init_h ----
        float (*wrow)[2 * D2] = (float (*)[2 * D2])smem;
        const int kt = (bid - NB_BETA) * 4;

        #pragma unroll
        for (int kk = 0; kk < 4; ++kk) {
            ((float4*)wrow[kk])[tid] =
                ((const float4*)(Wi + (size_t)(kt + kk) * (2 * D2)))[tid];
        }
        __syncthreads();

        const int b = tid >> 2;
        const int kk = tid & 3;
        const int k = kt + kk;
        const int vs = valid_sen[b];
        const int lbl = atten_label[vs];
        float acc = bi[k];
        const float4* hb = (const float4*)(h_n + b * D2);
        const float4* cb = (const float4*)(h_n1 + (lbl * B + vs) * D2);
        const float4* w0 = (const float4*)wrow[kk];
        const float4* w1 = (const float4*)(wrow[kk] + D2);
        #pragma unroll 4
        for (int d = 0; d < D2 / 4; ++d) {
            const float4 a = hb[d], w = w0[d];
            acc += a.x * w.x + a.y * w.y + a.z * w.z + a.w * w.w;
        }
        #pragma unroll 4
        for (int d = 0; d < D2 / 4; ++d) {
            const float4 a = cb[d], w = w1[d];
            acc += a.x * w.x + a.y * w.y + a.z * w.z + a.w * w.w;
        }
        out[OFF_INITH + b * DH + k] = acc;
    } else {
        // ---- selected_wiki_h gather + sen cast ----
        const int gb = bid - NB_BETA - NB_INITH;          // 0..511
        // block covers float4 indices [gb*2048, gb*2048+2048) = 16 rows, ONE b
        const int b = gb >> 3;                            // (gb*16)>>7
        const int vs = valid_sen[b];                      // wave-uniform -> scalar
        const int gi = vs * W + atten_label[vs];          // h1 row index (b fixed)

        // sen cast: first 32 gather blocks
        const int gid = gb * 256 + tid;
        if (gid < B * S) {
            const int sb = gid >> 7, ss = gid & 127;
            const int svs = valid_sen[sb];
            out[OFF_SEN + gid] = (float)wiki_sen[(svs * W + atten_label[svs]) * S + ss];
        }

        // 8 independent nt-loads, then 8 nt-stores (MLP)
        floatx4 v[8];
        int q[8];
        #pragma unroll
        for (int j = 0; j < 8; ++j) {
            q[j] = gb * 2048 + j * 256 + tid;             // float4 index
            const int t = q[j] >> 7;                      // row (b,s)
            const int s = t & 127;
            const int d4 = q[j] & 127;
            const floatx4* src =
                (const floatx4*)(h1 + ((size_t)(s * (B * W) + gi)) * D2);
            v[j] = __builtin_nontemporal_load(&src[d4]);
        }
        #pragma unroll
        for (int j = 0; j < 8; ++j) {
            __builtin_nontemporal_store(v[j], &((floatx4*)(out + OFF_SWH))[q[j]]);
        }
    }

    // ---- grid-wide barrier, then block 0 wave 0 finalizes the loss ----
    cg::this_grid().sync();

    if (bid == 0 && tid < 64) {
        const float nll_t = __uint_as_float(atomicOr(&ws[tid], 0u));
        const float cnt_t = __uint_as_float(atomicOr(&ws[B + tid], 0u));
        float sn = cnt_t * nll_t;
        float sc = cnt_t;
        #pragma unroll
        for (int m = 32; m >= 1; m >>= 1) {
            sn += __shfl_xor(sn, m);
            sc += __shfl_xor(sc, m);
        }
        if (tid == 0) out[OFF_LOSS] = (sc > 0.0f) ? sn / fmaxf(sc, 1.0f) : 0.0f;
    }
}

extern "C" void kernel_launch(void* const* d_in, const int* in_sizes, int n_in,
                              void* d_out, int out_size, void* d_ws, size_t ws_size,
                              hipStream_t stream) {
    // input order: i, valid_sen, reverse_valid_sen, wiki_sen, wiki_num,
    //              h1, h_n1, atten_label, h, h_n, W_init, b_init
    const int* valid_sen   = (const int*)d_in[1];
    const int* wiki_sen    = (const int*)d_in[3];
    const float* h1        = (const float*)d_in[5];
    const float* h_n1      = (const float*)d_in[6];
    const int* atten_label = (const int*)d_in[7];
    const float* h_n       = (const float*)d_in[9];
    const float* Wi        = (const float*)d_in[10];
    const float* bi        = (const float*)d_in[11];
    float* out = (float*)d_out;
    unsigned* ws = (unsigned*)d_ws;

    void* args[] = {(void*)&h1, (void*)&h_n1, (void*)&h_n, (void*)&Wi,
                    (void*)&bi, (void*)&wiki_sen, (void*)&valid_sen,
                    (void*)&atten_label, (void*)&out, (void*)&ws};
    hipLaunchCooperativeKernel((const void*)k_fused, dim3(NB_TOTAL), dim3(256),
                               args, 0, stream);
}

// Round 11
// 21.534 us; speedup vs baseline: 6.1077x; 6.1077x over previous
//
#include <hip/hip_runtime.h>

#define S 128
#define B 64
#define W 32
#define D2 512
#define DH 512

typedef float floatx4 __attribute__((ext_vector_type(4)));

// d_out layout (floats), concatenated in reference return order
#define OFF_SEN 0
#define OFF_SWH (B * S)                      // 8192
#define OFF_INITH (OFF_SWH + B * S * D2)     // 4202496
#define OFF_CV (OFF_INITH + B * DH)          // 4235264
#define OFF_LOSS (OFF_CV + B * D2)           // 4268032

// ws layout (NO initialization required, robust to any initial contents):
//   u32[0..63]   nll bits   (atomicExch overwrite each call before any read)
//   u32[64..127] vmask bits (same)
//   u32[128]     arrival counter; finalizer = the arrival with (old&63)==63,
//                which fires exactly once per call for ANY starting value
//                (64 consecutive increments cover every residue mod 64 once;
//                2^32 is divisible by 64 so wrap preserves residues).
// No spins, no waits: every thread runs a bounded instruction sequence.

// grid partition for the fused kernel
#define NB_BETA 64
#define NB_INITH 128
#define NB_GATHER 1024
#define NB_TOTAL (NB_BETA + NB_INITH + NB_GATHER)

__global__ __launch_bounds__(256) void k_fused(
    const float* __restrict__ h1, const float* __restrict__ h_n1,
    const float* __restrict__ h_n, const float* __restrict__ Wi,
    const float* __restrict__ bi, const int* __restrict__ wiki_sen,
    const int* __restrict__ valid_sen, const int* __restrict__ atten_label,
    float* __restrict__ out, unsigned* __restrict__ ws)
{
    __shared__ float smem[4 * 2 * D2];       // 16 KB (inith); beta uses prefix
    const int bid = blockIdx.x;
    const int tid = threadIdx.x;

    if (bid < NB_BETA) {
        // ---- beta / nll / cv; the 64th-arriving block finalizes the loss ----
        const int b = bid;
        const int lane = tid & 63;
        const int wv = tid >> 6;             // 4 waves
        const int vs = valid_sen[b];
        const int lbl = atten_label[vs];
        float* sbeta = smem;

        const float* hb = h_n + b * D2;
        const float4 hn0 = ((const float4*)hb)[lane];
        const float4 hn1 = ((const float4*)hb)[64 + lane];

        #pragma unroll
        for (int i = 0; i < 8; ++i) {
            const int w = wv * 8 + i;
            const float* row = h_n1 + (w * B + vs) * D2;
            const float4 a0 = ((const float4*)row)[lane];
            const float4 a1 = ((const float4*)row)[64 + lane];
            float p = a0.x * hn0.x + a0.y * hn0.y + a0.z * hn0.z + a0.w * hn0.w
                    + a1.x * hn1.x + a1.y * hn1.y + a1.z * hn1.z + a1.w * hn1.w;
            #pragma unroll
            for (int m = 32; m >= 1; m >>= 1) p += __shfl_xor(p, m);
            if (lane == 0) sbeta[w] = p;
        }

        // wiki_cv[b,:] = h_n1[lbl, vs, :]
        if (tid < 128) {
            const float4* src = (const float4*)(h_n1 + (lbl * B + vs) * D2);
            float4* dst = (float4*)(out + OFF_CV + b * D2);
            dst[tid] = src[tid];
        }
        __syncthreads();

        if (tid == 0) {
            float mx = sbeta[0];
            for (int w = 1; w < W; ++w) mx = fmaxf(mx, sbeta[w]);
            float Z = 0.0f;
            for (int w = 0; w < W; ++w) Z += expf(sbeta[w] - mx);
            const float nll = -(sbeta[lbl] - mx - logf(Z));
            const float vmask = (lbl != 0) ? 1.0f : 0.0f;
            // publish values (release: exch -> fence -> counter inc below)
            atomicExch(&ws[b], __float_as_uint(nll));
            atomicExch(&ws[B + b], __float_as_uint(vmask));
            __threadfence();
        }

        // wave 0: arrival count; the 64th arrival's wave reduces in parallel
        if (tid < 64) {
            unsigned old = 0;
            if (tid == 0) old = atomicAdd(&ws[2 * B], 1u);
            old = __shfl(old, 0);
            if ((old & 63u) == 63u) {
                __threadfence();             // acquire
                const float nll_t = __uint_as_float(atomicOr(&ws[tid], 0u));
                const float cnt_t = __uint_as_float(atomicOr(&ws[B + tid], 0u));
                float sn = cnt_t * nll_t;
                float sc = cnt_t;
                #pragma unroll
                for (int m = 32; m >= 1; m >>= 1) {
                    sn += __shfl_xor(sn, m);
                    sc += __shfl_xor(sc, m);
                }
                if (tid == 0)
                    out[OFF_LOSS] = (sc > 0.0f) ? sn / fmaxf(sc, 1.0f) : 0.0f;
            }
        }
    } else if (bid < NB_BETA + NB_INITH) {
        // ---- init_h ----
        float (*wrow)[2 * D2] = (float (*)[2 * D2])smem;
        const int kt = (bid - NB_BETA) * 4;

        #pragma unroll
        for (int kk = 0; kk < 4; ++kk) {
            ((float4*)wrow[kk])[tid] =
                ((const float4*)(Wi + (size_t)(kt + kk) * (2 * D2)))[tid];
        }
        __syncthreads();

        const int b = tid >> 2;
        const int kk = tid & 3;
        const int k = kt + kk;
        const int vs = valid_sen[b];
        const int lbl = atten_label[vs];
        float acc = bi[k];
        const float4* hb = (const float4*)(h_n + b * D2);
        const float4* cb = (const float4*)(h_n1 + (lbl * B + vs) * D2);
        const float4* w0 = (const float4*)wrow[kk];
        const float4* w1 = (const float4*)(wrow[kk] + D2);
        #pragma unroll 4
        for (int d = 0; d < D2 / 4; ++d) {
            const float4 a = hb[d], w = w0[d];
            acc += a.x * w.x + a.y * w.y + a.z * w.z + a.w * w.w;
        }
        #pragma unroll 4
        for (int d = 0; d < D2 / 4; ++d) {
            const float4 a = cb[d], w = w1[d];
            acc += a.x * w.x + a.y * w.y + a.z * w.z + a.w * w.w;
        }
        out[OFF_INITH + b * DH + k] = acc;
    } else {
        // ---- selected_wiki_h gather + sen cast ----
        const int gb = bid - NB_BETA - NB_INITH;          // 0..1023
        // block covers float4 indices [gb*1024, gb*1024+1024) = 8 rows, ONE b
        const int b = gb >> 4;
        const int vs = valid_sen[b];                      // wave-uniform -> scalar
        const int gi = vs * W + atten_label[vs];          // h1 row index (b fixed)

        // sen cast: first 32 gather blocks
        const int gid = gb * 256 + tid;
        if (gid < B * S) {
            const int sb = gid >> 7, ss = gid & 127;
            const int svs = valid_sen[sb];
            out[OFF_SEN + gid] = (float)wiki_sen[(svs * W + atten_label[svs]) * S + ss];
        }

        // 4 independent nt-loads, then 4 nt-stores
        floatx4 v[4];
        int q[4];
        #pragma unroll
        for (int j = 0; j < 4; ++j) {
            q[j] = gb * 1024 + j * 256 + tid;             // float4 index
            const int t = q[j] >> 7;                      // row (b,s)
            const int s = t & 127;
            const int d4 = q[j] & 127;
            const floatx4* src =
                (const floatx4*)(h1 + ((size_t)(s * (B * W) + gi)) * D2);
            v[j] = __builtin_nontemporal_load(&src[d4]);
        }
        #pragma unroll
        for (int j = 0; j < 4; ++j) {
            __builtin_nontemporal_store(v[j], &((floatx4*)(out + OFF_SWH))[q[j]]);
        }
    }
}

extern "C" void kernel_launch(void* const* d_in, const int* in_sizes, int n_in,
                              void* d_out, int out_size, void* d_ws, size_t ws_size,
                              hipStream_t stream) {
    // input order: i, valid_sen, reverse_valid_sen, wiki_sen, wiki_num,
    //              h1, h_n1, atten_label, h, h_n, W_init, b_init
    const int* valid_sen   = (const int*)d_in[1];
    const int* wiki_sen    = (const int*)d_in[3];
    const float* h1        = (const float*)d_in[5];
    const float* h_n1      = (const float*)d_in[6];
    const int* atten_label = (const int*)d_in[7];
    const float* h_n       = (const float*)d_in[9];
    const float* Wi        = (const float*)d_in[10];
    const float* bi        = (const float*)d_in[11];
    float* out = (float*)d_out;
    unsigned* ws = (unsigned*)d_ws;

    k_fused<<<NB_TOTAL, 256, 0, stream>>>(h1, h_n1, h_n, Wi, bi, wiki_sen,
                                          valid_sen, atten_label, out, ws);
}

// Round 12
// 21.051 us; speedup vs baseline: 6.2479x; 1.0230x over previous
//
#include <hip/hip_runtime.h>

#define S 128
#define B 64
#define W 32
#define D2 512
#define DH 512

typedef float floatx4 __attribute__((ext_vector_type(4)));

// d_out layout (floats), concatenated in reference return order
#define OFF_SEN 0
#define OFF_SWH (B * S)                      // 8192
#define OFF_INITH (OFF_SWH + B * S * D2)     // 4202496
#define OFF_CV (OFF_INITH + B * DH)          // 4235264
#define OFF_LOSS (OFF_CV + B * D2)           // 4268032

// ws layout (NO initialization required, robust to any initial contents):
//   u32[0..63]   nll bits   (atomicExch overwrite each call before any read)
//   u32[64..127] vmask bits (same)
//   u32[128]     arrival counter; finalizer = the arrival with (old&63)==63,
//                fires exactly once per call for ANY starting value.
// No spins, no waits: every thread runs a bounded instruction sequence.

// grid partition for the fused kernel
#define NB_BETA 64
#define NB_INITH 128
#define NB_GATHER 512
#define NB_TOTAL (NB_BETA + NB_INITH + NB_GATHER)

__global__ __launch_bounds__(256) void k_fused(
    const float* __restrict__ h1, const float* __restrict__ h_n1,
    const float* __restrict__ h_n, const float* __restrict__ Wi,
    const float* __restrict__ bi, const int* __restrict__ wiki_sen,
    const int* __restrict__ valid_sen, const int* __restrict__ atten_label,
    float* __restrict__ out, unsigned* __restrict__ ws)
{
    __shared__ float smem[4 * 2 * D2];       // 16 KB (inith); beta uses prefix
    const int bid = blockIdx.x;
    const int tid = threadIdx.x;

    if (bid < NB_BETA) {
        // ---- beta / nll / cv / sen; 64th-arriving block finalizes loss ----
        const int b = bid;
        const int lane = tid & 63;
        const int wv = tid >> 6;             // 4 waves
        const int vs = valid_sen[b];
        const int lbl = atten_label[vs];
        float* sbeta = smem;

        const float* hb = h_n + b * D2;
        const float4 hn0 = ((const float4*)hb)[lane];
        const float4 hn1 = ((const float4*)hb)[64 + lane];

        #pragma unroll
        for (int i = 0; i < 8; ++i) {
            const int w = wv * 8 + i;
            const float* row = h_n1 + (w * B + vs) * D2;
            const float4 a0 = ((const float4*)row)[lane];
            const float4 a1 = ((const float4*)row)[64 + lane];
            float p = a0.x * hn0.x + a0.y * hn0.y + a0.z * hn0.z + a0.w * hn0.w
                    + a1.x * hn1.x + a1.y * hn1.y + a1.z * hn1.z + a1.w * hn1.w;
            #pragma unroll
            for (int m = 32; m >= 1; m >>= 1) p += __shfl_xor(p, m);
            if (lane == 0) sbeta[w] = p;
        }

        if (tid < 128) {
            // wiki_cv[b,:] = h_n1[lbl, vs, :]
            const float4* src = (const float4*)(h_n1 + (lbl * B + vs) * D2);
            float4* dst = (float4*)(out + OFF_CV + b * D2);
            dst[tid] = src[tid];
        } else {
            // selected_wiki_sen[b,:] (vs, lbl already in scalar regs)
            const int s = tid - 128;
            out[OFF_SEN + b * S + s] = (float)wiki_sen[(vs * W + lbl) * S + s];
        }
        __syncthreads();

        if (tid == 0) {
            float mx = sbeta[0];
            for (int w = 1; w < W; ++w) mx = fmaxf(mx, sbeta[w]);
            float Z = 0.0f;
            for (int w = 0; w < W; ++w) Z += expf(sbeta[w] - mx);
            const float nll = -(sbeta[lbl] - mx - logf(Z));
            const float vmask = (lbl != 0) ? 1.0f : 0.0f;
            // publish values (release: exch -> fence -> counter inc below)
            atomicExch(&ws[b], __float_as_uint(nll));
            atomicExch(&ws[B + b], __float_as_uint(vmask));
            __threadfence();
        }

        // wave 0: arrival count; the 64th arrival's wave reduces in parallel
        if (tid < 64) {
            unsigned old = 0;
            if (tid == 0) old = atomicAdd(&ws[2 * B], 1u);
            old = __shfl(old, 0);
            if ((old & 63u) == 63u) {
                __threadfence();             // acquire
                const float nll_t = __uint_as_float(atomicOr(&ws[tid], 0u));
                const float cnt_t = __uint_as_float(atomicOr(&ws[B + tid], 0u));
                float sn = cnt_t * nll_t;
                float sc = cnt_t;
                #pragma unroll
                for (int m = 32; m >= 1; m >>= 1) {
                    sn += __shfl_xor(sn, m);
                    sc += __shfl_xor(sc, m);
                }
                if (tid == 0)
                    out[OFF_LOSS] = (sc > 0.0f) ? sn / fmaxf(sc, 1.0f) : 0.0f;
            }
        }
    } else if (bid < NB_BETA + NB_INITH) {
        // ---- init_h ----
        float (*wrow)[2 * D2] = (float (*)[2 * D2])smem;
        const int kt = (bid - NB_BETA) * 4;

        #pragma unroll
        for (int kk = 0; kk < 4; ++kk) {
            ((float4*)wrow[kk])[tid] =
                ((const float4*)(Wi + (size_t)(kt + kk) * (2 * D2)))[tid];
        }
        __syncthreads();

        const int b = tid >> 2;
        const int kk = tid & 3;
        const int k = kt + kk;
        const int vs = valid_sen[b];
        const int lbl = atten_label[vs];
        float acc = bi[k];
        const float4* hb = (const float4*)(h_n + b * D2);
        const float4* cb = (const float4*)(h_n1 + (lbl * B + vs) * D2);
        const float4* w0 = (const float4*)wrow[kk];
        const float4* w1 = (const float4*)(wrow[kk] + D2);
        #pragma unroll 4
        for (int d = 0; d < D2 / 4; ++d) {
            const float4 a = hb[d], w = w0[d];
            acc += a.x * w.x + a.y * w.y + a.z * w.z + a.w * w.w;
        }
        #pragma unroll 4
        for (int d = 0; d < D2 / 4; ++d) {
            const float4 a = cb[d], w = w1[d];
            acc += a.x * w.x + a.y * w.y + a.z * w.z + a.w * w.w;
        }
        out[OFF_INITH + b * DH + k] = acc;
    } else {
        // ---- selected_wiki_h gather: 8 independent nt-loads then 8 nt-stores ----
        const int gb = bid - NB_BETA - NB_INITH;          // 0..511
        // block covers float4 indices [gb*2048, gb*2048+2048) = 16 rows, ONE b
        const int b = gb >> 3;
        const int vs = valid_sen[b];                      // wave-uniform -> scalar
        const int gi = vs * W + atten_label[vs];          // h1 row index (b fixed)

        floatx4 v[8];
        int q[8];
        #pragma unroll
        for (int j = 0; j < 8; ++j) {
            q[j] = gb * 2048 + j * 256 + tid;             // float4 index
            const int t = q[j] >> 7;                      // row (b,s)
            const int s = t & 127;
            const int d4 = q[j] & 127;
            const floatx4* src =
                (const floatx4*)(h1 + ((size_t)(s * (B * W) + gi)) * D2);
            v[j] = __builtin_nontemporal_load(&src[d4]);
        }
        #pragma unroll
        for (int j = 0; j < 8; ++j) {
            __builtin_nontemporal_store(v[j], &((floatx4*)(out + OFF_SWH))[q[j]]);
        }
    }
}

extern "C" void kernel_launch(void* const* d_in, const int* in_sizes, int n_in,
                              void* d_out, int out_size, void* d_ws, size_t ws_size,
                              hipStream_t stream) {
    // input order: i, valid_sen, reverse_valid_sen, wiki_sen, wiki_num,
    //              h1, h_n1, atten_label, h, h_n, W_init, b_init
    const int* valid_sen   = (const int*)d_in[1];
    const int* wiki_sen    = (const int*)d_in[3];
    const float* h1        = (const float*)d_in[5];
    const float* h_n1      = (const float*)d_in[6];
    const int* atten_label = (const int*)d_in[7];
    const float* h_n       = (const float*)d_in[9];
    const float* Wi        = (const float*)d_in[10];
    const float* bi        = (const float*)d_in[11];
    float* out = (float*)d_out;
    unsigned* ws = (unsigned*)d_ws;

    k_fused<<<NB_TOTAL, 256, 0, stream>>>(h1, h_n1, h_n, Wi, bi, wiki_sen,
                                          valid_sen, atten_label, out, ws);
}